// Round 1
// baseline (710.011 us; speedup 1.0000x reference)
//
#include <hip/hip_runtime.h>
#include <math.h>

#define HC 256
#define NEG_SLOPE 0.2f
#define BM 64
#define BN 64
#define BK 16

// ---------- edge dtype detection (int32 vs int64) ----------
__global__ void detect_i64_kernel(const int* __restrict__ e, int* __restrict__ flag, int nCheck) {
  if (blockIdx.x == 0 && threadIdx.x == 0) {
    int nz = 0;
    for (int i = 0; i < nCheck; ++i) nz += (e[2 * i + 1] != 0);
    *flag = (nz == 0) ? 1 : 0;  // all-high-words-zero => int64
  }
}

__device__ __forceinline__ int edge_val(const void* p, int is64, long long idx) {
  return is64 ? (int)((const long long*)p)[idx] : ((const int*)p)[idx];
}

// ---------- CSR build ----------
__global__ void zero_i32(int* __restrict__ p, int n) {
  int i = blockIdx.x * blockDim.x + threadIdx.x;
  if (i < n) p[i] = 0;
}

__global__ void count_kernel(const void* __restrict__ edges, const int* __restrict__ flag,
                             int* __restrict__ counts, int E) {
  int e = blockIdx.x * blockDim.x + threadIdx.x;
  if (e >= E) return;
  int is64 = *flag;
  int dst = edge_val(edges, is64, (long long)E + e);
  atomicAdd(&counts[dst], 1);
}

__global__ __launch_bounds__(1024) void scan_kernel(const int* __restrict__ counts,
                                                    int* __restrict__ row_ptr, int N) {
  __shared__ int sh[1024];
  __shared__ int carry_s;
  int t = threadIdx.x;
  if (t == 0) carry_s = 0;
  __syncthreads();
  for (int base = 0; base < N; base += 1024) {
    int v = (base + t < N) ? counts[base + t] : 0;
    sh[t] = v;
    __syncthreads();
    for (int off = 1; off < 1024; off <<= 1) {
      int y = (t >= off) ? sh[t - off] : 0;
      __syncthreads();
      if (t >= off) sh[t] += y;
      __syncthreads();
    }
    int incl = sh[t];
    int carry = carry_s;
    if (base + t < N) row_ptr[base + t] = carry + incl - v;  // exclusive
    __syncthreads();
    if (t == 1023) carry_s = carry + incl;
    __syncthreads();
  }
  if (t == 0) row_ptr[N] = carry_s;
}

__global__ void copy_i32(const int* __restrict__ a, int* __restrict__ b, int n) {
  int i = blockIdx.x * blockDim.x + threadIdx.x;
  if (i < n) b[i] = a[i];
}

__global__ void fill_kernel(const void* __restrict__ edges, const int* __restrict__ flag,
                            int* __restrict__ cursor, int* __restrict__ csr_src, int E) {
  int e = blockIdx.x * blockDim.x + threadIdx.x;
  if (e >= E) return;
  int is64 = *flag;
  int src = edge_val(edges, is64, e);
  int dst = edge_val(edges, is64, (long long)E + e);
  int pos = atomicAdd(&cursor[dst], 1);
  csr_src[pos] = src;
}

// ---------- fp32 tiled GEMM: C[M,256] = A[M,256] @ B[256,256] + bias ----------
__global__ __launch_bounds__(256) void sgemm_bias_kernel(
    const float* __restrict__ A, const float* __restrict__ B,
    const float* __restrict__ bias, float* __restrict__ C, int M) {
  __shared__ float As[BK][BM + 4];
  __shared__ float Bs[BK][BN];
  const int tid = threadIdx.x;
  const int bm = blockIdx.x * BM;
  const int bn = blockIdx.y * BN;
  const int tx = tid & 15, ty = tid >> 4;
  const int r0 = ty * 4, c0 = tx * 4;
  const int la_m = tid >> 2;
  const int la_k = (tid & 3) * 4;
  const int lb_k = tid >> 4;
  const int lb_n = (tid & 15) * 4;
  float acc[4][4] = {{0.f}};
  for (int k0 = 0; k0 < 256; k0 += BK) {
    float4 av = make_float4(0.f, 0.f, 0.f, 0.f);
    int arow = bm + la_m;
    if (arow < M) av = *(const float4*)(A + (size_t)arow * 256 + k0 + la_k);
    float4 bv = *(const float4*)(B + (size_t)(k0 + lb_k) * 256 + bn + lb_n);
    __syncthreads();
    As[la_k + 0][la_m] = av.x;
    As[la_k + 1][la_m] = av.y;
    As[la_k + 2][la_m] = av.z;
    As[la_k + 3][la_m] = av.w;
    *(float4*)&Bs[lb_k][lb_n] = bv;
    __syncthreads();
#pragma unroll
    for (int kk = 0; kk < BK; ++kk) {
      float4 a = *(const float4*)&As[kk][r0];
      float4 b = *(const float4*)&Bs[kk][c0];
      acc[0][0] += a.x * b.x; acc[0][1] += a.x * b.y; acc[0][2] += a.x * b.z; acc[0][3] += a.x * b.w;
      acc[1][0] += a.y * b.x; acc[1][1] += a.y * b.y; acc[1][2] += a.y * b.z; acc[1][3] += a.y * b.w;
      acc[2][0] += a.z * b.x; acc[2][1] += a.z * b.y; acc[2][2] += a.z * b.z; acc[2][3] += a.z * b.w;
      acc[3][0] += a.w * b.x; acc[3][1] += a.w * b.y; acc[3][2] += a.w * b.z; acc[3][3] += a.w * b.w;
    }
  }
  float4 bs4 = *(const float4*)(bias + bn + c0);
#pragma unroll
  for (int i = 0; i < 4; ++i) {
    int row = bm + r0 + i;
    if (row < M) {
      float4 o;
      o.x = acc[i][0] + bs4.x;
      o.y = acc[i][1] + bs4.y;
      o.z = acc[i][2] + bs4.z;
      o.w = acc[i][3] + bs4.w;
      *(float4*)(C + (size_t)row * 256 + bn + c0) = o;
    }
  }
}

// ---------- fused GATv2 layer: online softmax over CSR neighbors + relu ----------
// one block (256 thr) per dst node; wave w = head w, lane = channel within head
__global__ __launch_bounds__(256) void gat_fused_kernel(
    const float* __restrict__ h, const float* __restrict__ att,
    const int* __restrict__ row_ptr, const int* __restrict__ csr_src,
    float* __restrict__ out, int N) {
  int node = blockIdx.x;
  if (node >= N) return;
  int t = threadIdx.x;
  float hi_v = h[(size_t)node * HC + t];
  float a_t = att[t];
  int beg = row_ptr[node], end = row_ptr[node + 1];
  float m = -INFINITY, d = 0.f, S = 0.f;
  for (int e = beg; e < end; ++e) {
    int j = csr_src[e];
    float hj = h[(size_t)j * HC + t];
    float s = hi_v + hj;
    float lr = (s > 0.f) ? s : NEG_SLOPE * s;
    float p = lr * a_t;
#pragma unroll
    for (int off = 32; off > 0; off >>= 1) p += __shfl_xor(p, off, 64);
    float mn = fmaxf(m, p);
    float scl = __expf(m - mn);
    float w = __expf(p - mn);
    d = d * scl + w;
    S = S * scl + w * hj;
    m = mn;
  }
  float o = (d > 0.f) ? (S / d) : 0.f;
  out[(size_t)node * HC + t] = fmaxf(o, 0.f);  // relu after each GAT layer
}

// ---------- fold post_mp: Wf = Wp1@Wp2, bf = bp1@Wp2 + bp2 ----------
__global__ __launch_bounds__(256) void fuse_w_kernel(
    const float* __restrict__ Wp1, const float* __restrict__ bp1,
    const float* __restrict__ Wp2, const float* __restrict__ bp2,
    float* __restrict__ Wf, float* __restrict__ bf) {
  int k = threadIdx.x;
  float acc[32];
#pragma unroll
  for (int o = 0; o < 32; ++o) acc[o] = 0.f;
  for (int l = 0; l < 64; ++l) {
    float w1 = Wp1[k * 64 + l];
#pragma unroll
    for (int o = 0; o < 32; ++o) acc[o] += w1 * Wp2[l * 32 + o];
  }
  for (int o = 0; o < 32; ++o) Wf[k * 32 + o] = acc[o];
  if (k < 32) {
    float s = bp2[k];
    for (int l = 0; l < 64; ++l) s += bp1[l] * Wp2[l * 32 + k];
    bf[k] = s;
  }
}

// ---------- post: out = sigmoid(g @ Wf + bf) ----------
__global__ __launch_bounds__(256) void post_kernel(
    const float* __restrict__ g, const float* __restrict__ Wf,
    const float* __restrict__ bf, float* __restrict__ out, int Nn) {
  __shared__ float sW[256 * 32];
  __shared__ float sg[8][256];
  for (int i = threadIdx.x; i < 256 * 32; i += 256) sW[i] = Wf[i];
  int o = threadIdx.x & 31, ln = threadIdx.x >> 5;
  float bo = bf[o];
  for (int base = blockIdx.x * 8; base < Nn; base += gridDim.x * 8) {
    __syncthreads();
    for (int i = threadIdx.x; i < 8 * 256; i += 256) {
      int r = i >> 8, c = i & 255;
      int node = base + r;
      sg[r][c] = (node < Nn) ? g[(size_t)node * 256 + c] : 0.f;
    }
    __syncthreads();
    int node = base + ln;
    if (node < Nn) {
      float acc = bo;
#pragma unroll 8
      for (int k = 0; k < 256; ++k) acc += sg[ln][k] * sW[k * 32 + o];
      out[(size_t)node * 32 + o] = 1.f / (1.f + __expf(-acc));
    }
  }
}

extern "C" void kernel_launch(void* const* d_in, const int* in_sizes, int n_in,
                              void* d_out, int out_size, void* d_ws, size_t ws_size,
                              hipStream_t stream) {
  const float* x    = (const float*)d_in[0];
  const void*  ei   = d_in[1];
  const float* W1   = (const float*)d_in[2];
  const float* b1   = (const float*)d_in[3];
  const float* att1 = (const float*)d_in[4];
  const float* W2   = (const float*)d_in[5];
  const float* b2   = (const float*)d_in[6];
  const float* att2 = (const float*)d_in[7];
  const float* Wp1  = (const float*)d_in[8];
  const float* bp1  = (const float*)d_in[9];
  const float* Wp2  = (const float*)d_in[10];
  const float* bp2  = (const float*)d_in[11];
  const int N = in_sizes[0] / 256;
  const int E = in_sizes[1] / 2;
  float* outp = (float*)d_out;

  char* ws = (char*)d_ws;
  size_t off = 0;
  auto alloc = [&](size_t bytes) {
    char* p = ws + off;
    off = (off + bytes + 255) & ~(size_t)255;
    return p;
  };
  float* h       = (float*)alloc((size_t)N * 256 * 4);
  float* g       = (float*)alloc((size_t)N * 256 * 4);
  int*   row_ptr = (int*)alloc((size_t)(N + 1) * 4);
  int*   cursor  = (int*)alloc((size_t)N * 4);
  int*   csr     = (int*)alloc((size_t)E * 4);
  float* Wf      = (float*)alloc(256 * 32 * 4);
  float* bf      = (float*)alloc(32 * 4);
  int*   flag    = (int*)alloc(4);

  const int nb = (N + 255) / 256;
  const int eb = (E + 255) / 256;

  hipLaunchKernelGGL(detect_i64_kernel, dim3(1), dim3(1), 0, stream, (const int*)ei, flag, 64);
  hipLaunchKernelGGL(zero_i32, dim3(nb), dim3(256), 0, stream, cursor, N);
  hipLaunchKernelGGL(count_kernel, dim3(eb), dim3(256), 0, stream, ei, flag, cursor, E);
  hipLaunchKernelGGL(scan_kernel, dim3(1), dim3(1024), 0, stream, cursor, row_ptr, N);
  hipLaunchKernelGGL(copy_i32, dim3(nb), dim3(256), 0, stream, row_ptr, cursor, N);
  hipLaunchKernelGGL(fill_kernel, dim3(eb), dim3(256), 0, stream, ei, flag, cursor, csr, E);

  dim3 gg((N + BM - 1) / BM, 256 / BN);
  hipLaunchKernelGGL(sgemm_bias_kernel, gg, dim3(256), 0, stream, x, W1, b1, h, N);
  hipLaunchKernelGGL(gat_fused_kernel, dim3(N), dim3(256), 0, stream, h, att1, row_ptr, csr, g, N);
  hipLaunchKernelGGL(sgemm_bias_kernel, gg, dim3(256), 0, stream, g, W2, b2, h, N);
  hipLaunchKernelGGL(gat_fused_kernel, dim3(N), dim3(256), 0, stream, h, att2, row_ptr, csr, g, N);
  hipLaunchKernelGGL(fuse_w_kernel, dim3(1), dim3(256), 0, stream, Wp1, bp1, Wp2, bp2, Wf, bf);
  hipLaunchKernelGGL(post_kernel, dim3(1024), dim3(256), 0, stream, g, Wf, bf, outp, N);
}

// Round 2
// 464.632 us; speedup vs baseline: 1.5281x; 1.5281x over previous
//
#include <hip/hip_runtime.h>
#include <math.h>

#define HC 256
#define NEG_SLOPE 0.2f
#define BM 64
#define BN 64
#define BK 16

// ---------- edge dtype detection (int32 vs int64) ----------
__global__ void detect_i64_kernel(const int* __restrict__ e, int* __restrict__ flag, int nCheck) {
  if (blockIdx.x == 0 && threadIdx.x == 0) {
    int nz = 0;
    for (int i = 0; i < nCheck; ++i) nz += (e[2 * i + 1] != 0);
    *flag = (nz == 0) ? 1 : 0;  // all-high-words-zero => int64
  }
}

__device__ __forceinline__ int edge_val(const void* p, int is64, long long idx) {
  return is64 ? (int)((const long long*)p)[idx] : ((const int*)p)[idx];
}

// ---------- CSR build ----------
__global__ void zero_i32(int* __restrict__ p, int n) {
  int i = blockIdx.x * blockDim.x + threadIdx.x;
  if (i < n) p[i] = 0;
}

__global__ void count_kernel(const void* __restrict__ edges, const int* __restrict__ flag,
                             int* __restrict__ counts, int E) {
  int e = blockIdx.x * blockDim.x + threadIdx.x;
  if (e >= E) return;
  int is64 = *flag;
  int dst = edge_val(edges, is64, (long long)E + e);
  atomicAdd(&counts[dst], 1);
}

__device__ __forceinline__ int wave_incl_scan(int v) {
  int lane = threadIdx.x & 63;
#pragma unroll
  for (int off = 1; off < 64; off <<= 1) {
    int y = __shfl_up(v, off, 64);
    if (lane >= off) v += y;
  }
  return v;
}

// hierarchical scan: scan1 (per-1024 block) -> scan2 (partials) -> scan3 (add)
__global__ __launch_bounds__(1024) void scan1_kernel(const int* __restrict__ counts,
                                                     int* __restrict__ excl,
                                                     int* __restrict__ partials, int N) {
  __shared__ int wsum[16];
  int i = blockIdx.x * 1024 + threadIdx.x;
  int wid = threadIdx.x >> 6, lane = threadIdx.x & 63;
  int v = (i < N) ? counts[i] : 0;
  int incl = wave_incl_scan(v);
  if (lane == 63) wsum[wid] = incl;
  __syncthreads();
  if (wid == 0) {
    int s = (lane < 16) ? wsum[lane] : 0;
    s = wave_incl_scan(s);
    if (lane < 16) wsum[lane] = s;
  }
  __syncthreads();
  int base = (wid > 0) ? wsum[wid - 1] : 0;
  if (i < N) excl[i] = base + incl - v;
  if (threadIdx.x == 1023) partials[blockIdx.x] = base + incl;
}

__global__ void scan2_kernel(int* __restrict__ partials, int P) {
  int lane = threadIdx.x;
  if (P <= 64) {
    int v = (lane < P) ? partials[lane] : 0;
    int incl = wave_incl_scan(v);
    if (lane < P) partials[lane] = incl - v;
  } else if (lane == 0) {
    int run = 0;
    for (int i = 0; i < P; ++i) { int v = partials[i]; partials[i] = run; run += v; }
  }
}

__global__ void scan3_kernel(int* __restrict__ excl, const int* __restrict__ partials,
                             int N, int E) {
  int i = blockIdx.x * blockDim.x + threadIdx.x;
  if (i < N) excl[i] += partials[i >> 10];
  if (i == 0) excl[N] = E;
}

__global__ void copy_i32(const int* __restrict__ a, int* __restrict__ b, int n) {
  int i = blockIdx.x * blockDim.x + threadIdx.x;
  if (i < n) b[i] = a[i];
}

__global__ void fill_kernel(const void* __restrict__ edges, const int* __restrict__ flag,
                            int* __restrict__ cursor, int* __restrict__ csr_src, int E) {
  int e = blockIdx.x * blockDim.x + threadIdx.x;
  if (e >= E) return;
  int is64 = *flag;
  int src = edge_val(edges, is64, e);
  int dst = edge_val(edges, is64, (long long)E + e);
  int pos = atomicAdd(&cursor[dst], 1);
  csr_src[pos] = src;
}

// ---------- fp32 tiled GEMM: C[M,256] = A[M,256] @ B[256,256] + bias ----------
__global__ __launch_bounds__(256) void sgemm_bias_kernel(
    const float* __restrict__ A, const float* __restrict__ B,
    const float* __restrict__ bias, float* __restrict__ C, int M) {
  __shared__ float As[BK][BM + 4];
  __shared__ float Bs[BK][BN];
  const int tid = threadIdx.x;
  const int bm = blockIdx.x * BM;
  const int bn = blockIdx.y * BN;
  const int tx = tid & 15, ty = tid >> 4;
  const int r0 = ty * 4, c0 = tx * 4;
  const int la_m = tid >> 2;
  const int la_k = (tid & 3) * 4;
  const int lb_k = tid >> 4;
  const int lb_n = (tid & 15) * 4;
  float acc[4][4] = {{0.f}};
  for (int k0 = 0; k0 < 256; k0 += BK) {
    float4 av = make_float4(0.f, 0.f, 0.f, 0.f);
    int arow = bm + la_m;
    if (arow < M) av = *(const float4*)(A + (size_t)arow * 256 + k0 + la_k);
    float4 bv = *(const float4*)(B + (size_t)(k0 + lb_k) * 256 + bn + lb_n);
    __syncthreads();
    As[la_k + 0][la_m] = av.x;
    As[la_k + 1][la_m] = av.y;
    As[la_k + 2][la_m] = av.z;
    As[la_k + 3][la_m] = av.w;
    *(float4*)&Bs[lb_k][lb_n] = bv;
    __syncthreads();
#pragma unroll
    for (int kk = 0; kk < BK; ++kk) {
      float4 a = *(const float4*)&As[kk][r0];
      float4 b = *(const float4*)&Bs[kk][c0];
      acc[0][0] += a.x * b.x; acc[0][1] += a.x * b.y; acc[0][2] += a.x * b.z; acc[0][3] += a.x * b.w;
      acc[1][0] += a.y * b.x; acc[1][1] += a.y * b.y; acc[1][2] += a.y * b.z; acc[1][3] += a.y * b.w;
      acc[2][0] += a.z * b.x; acc[2][1] += a.z * b.y; acc[2][2] += a.z * b.z; acc[2][3] += a.z * b.w;
      acc[3][0] += a.w * b.x; acc[3][1] += a.w * b.y; acc[3][2] += a.w * b.z; acc[3][3] += a.w * b.w;
    }
  }
  float4 bs4 = *(const float4*)(bias + bn + c0);
#pragma unroll
  for (int i = 0; i < 4; ++i) {
    int row = bm + r0 + i;
    if (row < M) {
      float4 o;
      o.x = acc[i][0] + bs4.x;
      o.y = acc[i][1] + bs4.y;
      o.z = acc[i][2] + bs4.z;
      o.w = acc[i][3] + bs4.w;
      *(float4*)(C + (size_t)row * 256 + bn + c0) = o;
    }
  }
}

// ---------- fused GATv2 layer: 1 wave per node, 4 channels (float4) per lane ----------
// lane ln handles channels [4ln, 4ln+4); head = ln>>4; att-dot reduce = 4 shfl over 16 lanes
__global__ __launch_bounds__(256) void gat_fused_kernel(
    const float* __restrict__ h, const float* __restrict__ att,
    const int* __restrict__ row_ptr, const int* __restrict__ csr_src,
    float* __restrict__ out, int N) {
  int wid = threadIdx.x >> 6, ln = threadIdx.x & 63;
  int node = blockIdx.x * 4 + wid;
  if (node >= N) return;
  const float4 attv = *(const float4*)(att + ln * 4);
  const float4 hi = *(const float4*)(h + (size_t)node * HC + ln * 4);
  int beg = row_ptr[node], end = row_ptr[node + 1];
  float m = -INFINITY, d = 0.f;
  float4 S = make_float4(0.f, 0.f, 0.f, 0.f);
  if (beg < end) {
    int j = csr_src[beg];
    float4 hj = *(const float4*)(h + (size_t)j * HC + ln * 4);
    for (int e = beg; e < end; ++e) {
      int jn = 0;
      float4 hjn = make_float4(0.f, 0.f, 0.f, 0.f);
      bool more = (e + 1 < end);
      if (more) {  // prefetch next edge (wave-uniform branch)
        jn = csr_src[e + 1];
        hjn = *(const float4*)(h + (size_t)jn * HC + ln * 4);
      }
      float4 s4;
      s4.x = hi.x + hj.x; s4.y = hi.y + hj.y; s4.z = hi.z + hj.z; s4.w = hi.w + hj.w;
      float4 l4;
      l4.x = fmaxf(s4.x, NEG_SLOPE * s4.x);
      l4.y = fmaxf(s4.y, NEG_SLOPE * s4.y);
      l4.z = fmaxf(s4.z, NEG_SLOPE * s4.z);
      l4.w = fmaxf(s4.w, NEG_SLOPE * s4.w);
      float p = l4.x * attv.x + l4.y * attv.y + l4.z * attv.z + l4.w * attv.w;
#pragma unroll
      for (int off = 1; off < 16; off <<= 1) p += __shfl_xor(p, off, 64);
      float mn = fmaxf(m, p);
      float scl = __expf(m - mn);
      float w = __expf(p - mn);
      d = d * scl + w;
      S.x = S.x * scl + w * hj.x;
      S.y = S.y * scl + w * hj.y;
      S.z = S.z * scl + w * hj.z;
      S.w = S.w * scl + w * hj.w;
      m = mn;
      hj = hjn;
      j = jn;
    }
  }
  float inv = (d > 0.f) ? (1.f / d) : 0.f;
  float4 o;
  o.x = fmaxf(S.x * inv, 0.f);
  o.y = fmaxf(S.y * inv, 0.f);
  o.z = fmaxf(S.z * inv, 0.f);
  o.w = fmaxf(S.w * inv, 0.f);
  *(float4*)(out + (size_t)node * HC + ln * 4) = o;
}

// ---------- fold post_mp: Wf = Wp1@Wp2, bf = bp1@Wp2 + bp2 ----------
__global__ __launch_bounds__(256) void fuse_w_kernel(
    const float* __restrict__ Wp1, const float* __restrict__ bp1,
    const float* __restrict__ Wp2, const float* __restrict__ bp2,
    float* __restrict__ Wf, float* __restrict__ bf) {
  int k = threadIdx.x;
  float acc[32];
#pragma unroll
  for (int o = 0; o < 32; ++o) acc[o] = 0.f;
  for (int l = 0; l < 64; ++l) {
    float w1 = Wp1[k * 64 + l];
#pragma unroll
    for (int o = 0; o < 32; ++o) acc[o] += w1 * Wp2[l * 32 + o];
  }
  for (int o = 0; o < 32; ++o) Wf[k * 32 + o] = acc[o];
  if (k < 32) {
    float s = bp2[k];
    for (int l = 0; l < 64; ++l) s += bp1[l] * Wp2[l * 32 + k];
    bf[k] = s;
  }
}

// ---------- post: out = sigmoid(g @ Wf + bf) ----------
__global__ __launch_bounds__(256) void post_kernel(
    const float* __restrict__ g, const float* __restrict__ Wf,
    const float* __restrict__ bf, float* __restrict__ out, int Nn) {
  __shared__ float sW[256 * 32];
  __shared__ float sg[8][256];
  for (int i = threadIdx.x; i < 256 * 32; i += 256) sW[i] = Wf[i];
  int o = threadIdx.x & 31, ln = threadIdx.x >> 5;
  float bo = bf[o];
  for (int base = blockIdx.x * 8; base < Nn; base += gridDim.x * 8) {
    __syncthreads();
    for (int i = threadIdx.x; i < 8 * 256; i += 256) {
      int r = i >> 8, c = i & 255;
      int node = base + r;
      sg[r][c] = (node < Nn) ? g[(size_t)node * 256 + c] : 0.f;
    }
    __syncthreads();
    int node = base + ln;
    if (node < Nn) {
      float acc = bo;
#pragma unroll 8
      for (int k = 0; k < 256; ++k) acc += sg[ln][k] * sW[k * 32 + o];
      out[(size_t)node * 32 + o] = 1.f / (1.f + __expf(-acc));
    }
  }
}

extern "C" void kernel_launch(void* const* d_in, const int* in_sizes, int n_in,
                              void* d_out, int out_size, void* d_ws, size_t ws_size,
                              hipStream_t stream) {
  const float* x    = (const float*)d_in[0];
  const void*  ei   = d_in[1];
  const float* W1   = (const float*)d_in[2];
  const float* b1   = (const float*)d_in[3];
  const float* att1 = (const float*)d_in[4];
  const float* W2   = (const float*)d_in[5];
  const float* b2   = (const float*)d_in[6];
  const float* att2 = (const float*)d_in[7];
  const float* Wp1  = (const float*)d_in[8];
  const float* bp1  = (const float*)d_in[9];
  const float* Wp2  = (const float*)d_in[10];
  const float* bp2  = (const float*)d_in[11];
  const int N = in_sizes[0] / 256;
  const int E = in_sizes[1] / 2;
  float* outp = (float*)d_out;

  char* ws = (char*)d_ws;
  size_t off = 0;
  auto alloc = [&](size_t bytes) {
    char* p = ws + off;
    off = (off + bytes + 255) & ~(size_t)255;
    return p;
  };
  float* h        = (float*)alloc((size_t)N * 256 * 4);
  float* g        = (float*)alloc((size_t)N * 256 * 4);
  int*   row_ptr  = (int*)alloc((size_t)(N + 1) * 4);
  int*   cursor   = (int*)alloc((size_t)N * 4);
  int*   csr      = (int*)alloc((size_t)E * 4);
  int*   partials = (int*)alloc((size_t)((N + 1023) / 1024 + 1) * 4);
  float* Wf       = (float*)alloc(256 * 32 * 4);
  float* bf       = (float*)alloc(32 * 4);
  int*   flag     = (int*)alloc(4);

  const int nb  = (N + 255) / 256;
  const int eb  = (E + 255) / 256;
  const int P   = (N + 1023) / 1024;

  hipLaunchKernelGGL(detect_i64_kernel, dim3(1), dim3(1), 0, stream, (const int*)ei, flag, 64);
  hipLaunchKernelGGL(zero_i32, dim3(nb), dim3(256), 0, stream, cursor, N);
  hipLaunchKernelGGL(count_kernel, dim3(eb), dim3(256), 0, stream, ei, flag, cursor, E);
  hipLaunchKernelGGL(scan1_kernel, dim3(P), dim3(1024), 0, stream, cursor, row_ptr, partials, N);
  hipLaunchKernelGGL(scan2_kernel, dim3(1), dim3(64), 0, stream, partials, P);
  hipLaunchKernelGGL(scan3_kernel, dim3(nb), dim3(256), 0, stream, row_ptr, partials, N, E);
  hipLaunchKernelGGL(copy_i32, dim3(nb), dim3(256), 0, stream, row_ptr, cursor, N);
  hipLaunchKernelGGL(fill_kernel, dim3(eb), dim3(256), 0, stream, ei, flag, cursor, csr, E);

  dim3 gg((N + BM - 1) / BM, 256 / BN);
  hipLaunchKernelGGL(sgemm_bias_kernel, gg, dim3(256), 0, stream, x, W1, b1, h, N);
  hipLaunchKernelGGL(gat_fused_kernel, dim3((N + 3) / 4), dim3(256), 0, stream, h, att1, row_ptr, csr, g, N);
  hipLaunchKernelGGL(sgemm_bias_kernel, gg, dim3(256), 0, stream, g, W2, b2, h, N);
  hipLaunchKernelGGL(gat_fused_kernel, dim3((N + 3) / 4), dim3(256), 0, stream, h, att2, row_ptr, csr, g, N);
  hipLaunchKernelGGL(fuse_w_kernel, dim3(1), dim3(256), 0, stream, Wp1, bp1, Wp2, bp2, Wf, bf);
  hipLaunchKernelGGL(post_kernel, dim3(1024), dim3(256), 0, stream, g, Wf, bf, outp, N);
}

// Round 3
// 386.044 us; speedup vs baseline: 1.8392x; 1.2036x over previous
//
#include <hip/hip_runtime.h>
#include <hip/hip_bf16.h>
#include <math.h>

#define HC 256
#define NEG_SLOPE 0.2f

typedef __attribute__((ext_vector_type(8))) short s16x8;
typedef __attribute__((ext_vector_type(4))) float f32x4;

__device__ __forceinline__ unsigned short f2bf(float f) {
  __hip_bfloat16 b = __float2bfloat16(f);
  return *reinterpret_cast<unsigned short*>(&b);
}

// ---------- edge dtype detection (int32 vs int64) ----------
__global__ void detect_i64_kernel(const int* __restrict__ e, int* __restrict__ flag, int nCheck) {
  if (blockIdx.x == 0 && threadIdx.x == 0) {
    int nz = 0;
    for (int i = 0; i < nCheck; ++i) nz += (e[2 * i + 1] != 0);
    *flag = (nz == 0) ? 1 : 0;  // all-high-words-zero => int64
  }
}

__device__ __forceinline__ int edge_val(const void* p, int is64, long long idx) {
  return is64 ? (int)((const long long*)p)[idx] : ((const int*)p)[idx];
}

// ---------- CSR build ----------
__global__ void zero_i32(int* __restrict__ p, int n) {
  int i = blockIdx.x * blockDim.x + threadIdx.x;
  if (i < n) p[i] = 0;
}

__global__ void count_kernel(const void* __restrict__ edges, const int* __restrict__ flag,
                             int* __restrict__ counts, int E) {
  int e = blockIdx.x * blockDim.x + threadIdx.x;
  if (e >= E) return;
  int is64 = *flag;
  int dst = edge_val(edges, is64, (long long)E + e);
  atomicAdd(&counts[dst], 1);
}

__device__ __forceinline__ int wave_incl_scan(int v) {
  int lane = threadIdx.x & 63;
#pragma unroll
  for (int off = 1; off < 64; off <<= 1) {
    int y = __shfl_up(v, off, 64);
    if (lane >= off) v += y;
  }
  return v;
}

__global__ __launch_bounds__(1024) void scan1_kernel(const int* __restrict__ counts,
                                                     int* __restrict__ excl,
                                                     int* __restrict__ partials, int N) {
  __shared__ int wsum[16];
  int i = blockIdx.x * 1024 + threadIdx.x;
  int wid = threadIdx.x >> 6, lane = threadIdx.x & 63;
  int v = (i < N) ? counts[i] : 0;
  int incl = wave_incl_scan(v);
  if (lane == 63) wsum[wid] = incl;
  __syncthreads();
  if (wid == 0) {
    int s = (lane < 16) ? wsum[lane] : 0;
    s = wave_incl_scan(s);
    if (lane < 16) wsum[lane] = s;
  }
  __syncthreads();
  int base = (wid > 0) ? wsum[wid - 1] : 0;
  if (i < N) excl[i] = base + incl - v;
  if (threadIdx.x == 1023) partials[blockIdx.x] = base + incl;
}

__global__ void scan2_kernel(int* __restrict__ partials, int P) {
  int lane = threadIdx.x;
  if (P <= 64) {
    int v = (lane < P) ? partials[lane] : 0;
    int incl = wave_incl_scan(v);
    if (lane < P) partials[lane] = incl - v;
  } else if (lane == 0) {
    int run = 0;
    for (int i = 0; i < P; ++i) { int v = partials[i]; partials[i] = run; run += v; }
  }
}

__global__ void scan3_kernel(int* __restrict__ excl, const int* __restrict__ partials,
                             int N, int E) {
  int i = blockIdx.x * blockDim.x + threadIdx.x;
  if (i < N) excl[i] += partials[i >> 10];
  if (i == 0) excl[N] = E;
}

__global__ void copy_i32(const int* __restrict__ a, int* __restrict__ b, int n) {
  int i = blockIdx.x * blockDim.x + threadIdx.x;
  if (i < n) b[i] = a[i];
}

__global__ void fill_kernel(const void* __restrict__ edges, const int* __restrict__ flag,
                            int* __restrict__ cursor, int* __restrict__ csr_src, int E) {
  int e = blockIdx.x * blockDim.x + threadIdx.x;
  if (e >= E) return;
  int is64 = *flag;
  int src = edge_val(edges, is64, e);
  int dst = edge_val(edges, is64, (long long)E + e);
  int pos = atomicAdd(&cursor[dst], 1);
  csr_src[pos] = src;
}

// ---------- fp32 -> bf16 convert (8 elems/thread) ----------
__global__ __launch_bounds__(256) void conv_bf16_kernel(const float* __restrict__ in,
                                                        unsigned short* __restrict__ out, int n8) {
  int i = blockIdx.x * 256 + threadIdx.x;
  if (i >= n8) return;
  const float4 a = *(const float4*)(in + (size_t)i * 8);
  const float4 b = *(const float4*)(in + (size_t)i * 8 + 4);
  uint4 u;
  u.x = f2bf(a.x) | ((unsigned)f2bf(a.y) << 16);
  u.y = f2bf(a.z) | ((unsigned)f2bf(a.w) << 16);
  u.z = f2bf(b.x) | ((unsigned)f2bf(b.y) << 16);
  u.w = f2bf(b.z) | ((unsigned)f2bf(b.w) << 16);
  *(uint4*)(out + (size_t)i * 8) = u;
}

// ---------- weight transpose+convert: Wt[n][k] = bf16(W[k][n]), 256x256 ----------
__global__ __launch_bounds__(256) void wtrans_kernel(const float* __restrict__ W,
                                                     unsigned short* __restrict__ Wt) {
  int n = blockIdx.x, t = threadIdx.x;
  Wt[(size_t)n * 256 + t] = f2bf(W[(size_t)t * 256 + n]);
}

// ---------- bf16 MFMA GEMM: C[M,256] = A[M,256](bf16) @ Bt[256,256]^T(bf16) + bias ----------
// 128x128 tile, BK=64, 4 waves (2x2), 64x64 per wave, reg-staged dbuf LDS, XOR swizzle
__global__ __launch_bounds__(256) void mfma_gemm_kernel(
    const unsigned short* __restrict__ A, const unsigned short* __restrict__ Bt,
    const float* __restrict__ bias, float* __restrict__ C, int M) {
  __shared__ __align__(16) short As[2][128 * 64];
  __shared__ __align__(16) short Bs[2][128 * 64];
  const int t = threadIdx.x;
  const int l = t & 63, w = t >> 6;
  const int wr = w >> 1, wc = w & 1;
  const int m0 = blockIdx.y * 128, n0 = blockIdx.x * 128;
  const int l15 = l & 15, lg = l >> 4;

  // staging: issue i covers LDS chunk c = i*256+t (16B chunks); row=c>>3, cc=t&7
  // LDS[row][cc] holds global chunk (cc ^ (row&7)); row&7 == (t>>3)&7 for all i
  const int ccs = ((t & 7) ^ ((t >> 3) & 7)) * 8;  // source elem offset within 64-k tile
  int rowL[4], ldsI[4];
#pragma unroll
  for (int i = 0; i < 4; ++i) {
    rowL[i] = i * 32 + (t >> 3);
    ldsI[i] = (i * 256 + t) * 8;
  }

  f32x4 acc[4][4];
#pragma unroll
  for (int m = 0; m < 4; ++m)
#pragma unroll
    for (int n = 0; n < 4; ++n) acc[m][n] = (f32x4){0.f, 0.f, 0.f, 0.f};

  uint4 ra[4], rb[4];
  auto LOAD = [&](int ks) {
    int k0 = ks * 64;
#pragma unroll
    for (int i = 0; i < 4; ++i) {
      int ar = m0 + rowL[i];
      ar = (ar < M) ? ar : (M - 1);
      ra[i] = *(const uint4*)(A + (size_t)ar * 256 + k0 + ccs);
      rb[i] = *(const uint4*)(Bt + (size_t)(n0 + rowL[i]) * 256 + k0 + ccs);
    }
  };
  auto WRITE = [&](int buf) {
#pragma unroll
    for (int i = 0; i < 4; ++i) {
      *(uint4*)&As[buf][ldsI[i]] = ra[i];
      *(uint4*)&Bs[buf][ldsI[i]] = rb[i];
    }
  };

  // fragment row bases (in shorts); swz = (kk*4 + lanegroup) ^ (l&7), row&7 == l&7
  int rA[4], rB[4];
#pragma unroll
  for (int m = 0; m < 4; ++m) rA[m] = (wr * 64 + m * 16 + l15) * 64;
#pragma unroll
  for (int n = 0; n < 4; ++n) rB[n] = (wc * 64 + n * 16 + l15) * 64;
  const int swz0 = ((0 * 4 + lg) ^ (l & 7)) * 8;
  const int swz1 = ((1 * 4 + lg) ^ (l & 7)) * 8;

  LOAD(0);
  WRITE(0);
  __syncthreads();
  for (int ks = 0; ks < 4; ++ks) {
    if (ks < 3) LOAD(ks + 1);
    const int buf = ks & 1;
#pragma unroll
    for (int kk = 0; kk < 2; ++kk) {
      const int swz = kk ? swz1 : swz0;
      s16x8 a[4], b[4];
#pragma unroll
      for (int m = 0; m < 4; ++m) a[m] = *(const s16x8*)&As[buf][rA[m] + swz];
#pragma unroll
      for (int n = 0; n < 4; ++n) b[n] = *(const s16x8*)&Bs[buf][rB[n] + swz];
#pragma unroll
      for (int m = 0; m < 4; ++m)
#pragma unroll
        for (int n = 0; n < 4; ++n)
          acc[m][n] = __builtin_amdgcn_mfma_f32_16x16x32_bf16(a[m], b[n], acc[m][n], 0, 0, 0);
    }
    if (ks < 3) WRITE((ks + 1) & 1);  // other buffer than the one being read
    __syncthreads();
  }

  float bcol[4];
#pragma unroll
  for (int n = 0; n < 4; ++n) bcol[n] = bias[n0 + wc * 64 + n * 16 + l15];
#pragma unroll
  for (int m = 0; m < 4; ++m) {
    int baseRow = m0 + wr * 64 + m * 16 + lg * 4;
#pragma unroll
    for (int r = 0; r < 4; ++r) {
      int row = baseRow + r;
      if (row < M) {
#pragma unroll
        for (int n = 0; n < 4; ++n)
          C[(size_t)row * 256 + n0 + wc * 64 + n * 16 + l15] = acc[m][n][r] + bcol[n];
      }
    }
  }
}

// ---------- fused GATv2 layer: 1 wave per node, 4 channels (float4) per lane ----------
__global__ __launch_bounds__(256) void gat_fused_kernel(
    const float* __restrict__ h, const float* __restrict__ att,
    const int* __restrict__ row_ptr, const int* __restrict__ csr_src,
    float* __restrict__ out_f, unsigned short* __restrict__ out_bf, int N) {
  int wid = threadIdx.x >> 6, ln = threadIdx.x & 63;
  int node = blockIdx.x * 4 + wid;
  if (node >= N) return;
  const float4 attv = *(const float4*)(att + ln * 4);
  const float4 hi = *(const float4*)(h + (size_t)node * HC + ln * 4);
  int beg = row_ptr[node], end = row_ptr[node + 1];
  float m = -INFINITY, d = 0.f;
  float4 S = make_float4(0.f, 0.f, 0.f, 0.f);
  if (beg < end) {
    int j = csr_src[beg];
    float4 hj = *(const float4*)(h + (size_t)j * HC + ln * 4);
    for (int e = beg; e < end; ++e) {
      int jn = 0;
      float4 hjn = make_float4(0.f, 0.f, 0.f, 0.f);
      bool more = (e + 1 < end);
      if (more) {  // prefetch next edge (wave-uniform branch)
        jn = csr_src[e + 1];
        hjn = *(const float4*)(h + (size_t)jn * HC + ln * 4);
      }
      float4 s4;
      s4.x = hi.x + hj.x; s4.y = hi.y + hj.y; s4.z = hi.z + hj.z; s4.w = hi.w + hj.w;
      float4 l4;
      l4.x = fmaxf(s4.x, NEG_SLOPE * s4.x);
      l4.y = fmaxf(s4.y, NEG_SLOPE * s4.y);
      l4.z = fmaxf(s4.z, NEG_SLOPE * s4.z);
      l4.w = fmaxf(s4.w, NEG_SLOPE * s4.w);
      float p = l4.x * attv.x + l4.y * attv.y + l4.z * attv.z + l4.w * attv.w;
#pragma unroll
      for (int off = 1; off < 16; off <<= 1) p += __shfl_xor(p, off, 64);
      float mn = fmaxf(m, p);
      float scl = __expf(m - mn);
      float wgt = __expf(p - mn);
      d = d * scl + wgt;
      S.x = S.x * scl + wgt * hj.x;
      S.y = S.y * scl + wgt * hj.y;
      S.z = S.z * scl + wgt * hj.z;
      S.w = S.w * scl + wgt * hj.w;
      m = mn;
      hj = hjn;
      j = jn;
    }
  }
  float inv = (d > 0.f) ? (1.f / d) : 0.f;
  float4 o;
  o.x = fmaxf(S.x * inv, 0.f);
  o.y = fmaxf(S.y * inv, 0.f);
  o.z = fmaxf(S.z * inv, 0.f);
  o.w = fmaxf(S.w * inv, 0.f);
  if (out_f) *(float4*)(out_f + (size_t)node * HC + ln * 4) = o;
  if (out_bf) {
    ushort4 ub;
    ub.x = f2bf(o.x); ub.y = f2bf(o.y); ub.z = f2bf(o.z); ub.w = f2bf(o.w);
    *(ushort4*)(out_bf + (size_t)node * HC + ln * 4) = ub;
  }
}

// ---------- fold post_mp: Wf = Wp1@Wp2, bf = bp1@Wp2 + bp2 ----------
__global__ __launch_bounds__(256) void fuse_w_kernel(
    const float* __restrict__ Wp1, const float* __restrict__ bp1,
    const float* __restrict__ Wp2, const float* __restrict__ bp2,
    float* __restrict__ Wf, float* __restrict__ bf) {
  int k = threadIdx.x;
  float acc[32];
#pragma unroll
  for (int o = 0; o < 32; ++o) acc[o] = 0.f;
  for (int ll = 0; ll < 64; ++ll) {
    float w1 = Wp1[k * 64 + ll];
#pragma unroll
    for (int o = 0; o < 32; ++o) acc[o] += w1 * Wp2[ll * 32 + o];
  }
  for (int o = 0; o < 32; ++o) Wf[k * 32 + o] = acc[o];
  if (k < 32) {
    float s = bp2[k];
    for (int ll = 0; ll < 64; ++ll) s += bp1[ll] * Wp2[ll * 32 + k];
    bf[k] = s;
  }
}

// ---------- post: out = sigmoid(g @ Wf + bf) ----------
__global__ __launch_bounds__(256) void post_kernel(
    const float* __restrict__ g, const float* __restrict__ Wf,
    const float* __restrict__ bf, float* __restrict__ out, int Nn) {
  __shared__ float sW[256 * 32];
  __shared__ float sg[8][256];
  for (int i = threadIdx.x; i < 256 * 32; i += 256) sW[i] = Wf[i];
  int o = threadIdx.x & 31, ln = threadIdx.x >> 5;
  float bo = bf[o];
  for (int base = blockIdx.x * 8; base < Nn; base += gridDim.x * 8) {
    __syncthreads();
    for (int i = threadIdx.x; i < 8 * 256; i += 256) {
      int r = i >> 8, c = i & 255;
      int node = base + r;
      sg[r][c] = (node < Nn) ? g[(size_t)node * 256 + c] : 0.f;
    }
    __syncthreads();
    int node = base + ln;
    if (node < Nn) {
      float acc = bo;
#pragma unroll 8
      for (int k = 0; k < 256; ++k) acc += sg[ln][k] * sW[k * 32 + o];
      out[(size_t)node * 32 + o] = 1.f / (1.f + __expf(-acc));
    }
  }
}

extern "C" void kernel_launch(void* const* d_in, const int* in_sizes, int n_in,
                              void* d_out, int out_size, void* d_ws, size_t ws_size,
                              hipStream_t stream) {
  const float* x    = (const float*)d_in[0];
  const void*  ei   = d_in[1];
  const float* W1   = (const float*)d_in[2];
  const float* b1   = (const float*)d_in[3];
  const float* att1 = (const float*)d_in[4];
  const float* W2   = (const float*)d_in[5];
  const float* b2   = (const float*)d_in[6];
  const float* att2 = (const float*)d_in[7];
  const float* Wp1  = (const float*)d_in[8];
  const float* bp1  = (const float*)d_in[9];
  const float* Wp2  = (const float*)d_in[10];
  const float* bp2  = (const float*)d_in[11];
  const int N = in_sizes[0] / 256;
  const int E = in_sizes[1] / 2;
  float* outp = (float*)d_out;

  char* ws = (char*)d_ws;
  size_t off = 0;
  auto alloc = [&](size_t bytes) {
    char* p = ws + off;
    off = (off + bytes + 255) & ~(size_t)255;
    return p;
  };
  float* h        = (float*)alloc((size_t)N * 256 * 4);
  float* g        = (float*)alloc((size_t)N * 256 * 4);
  unsigned short* abf = (unsigned short*)alloc((size_t)N * 256 * 2);  // x_bf, then g_bf
  int*   row_ptr  = (int*)alloc((size_t)(N + 1) * 4);
  int*   cursor   = (int*)alloc((size_t)N * 4);
  int*   csr      = (int*)alloc((size_t)E * 4);
  int*   partials = (int*)alloc((size_t)((N + 1023) / 1024 + 1) * 4);
  unsigned short* W1t = (unsigned short*)alloc(256 * 256 * 2);
  unsigned short* W2t = (unsigned short*)alloc(256 * 256 * 2);
  float* Wf       = (float*)alloc(256 * 32 * 4);
  float* bfv      = (float*)alloc(32 * 4);
  int*   flag     = (int*)alloc(4);

  const int nb = (N + 255) / 256;
  const int eb = (E + 255) / 256;
  const int P  = (N + 1023) / 1024;
  const int n8 = (N * 256) / 8;

  hipLaunchKernelGGL(detect_i64_kernel, dim3(1), dim3(1), 0, stream, (const int*)ei, flag, 64);
  hipLaunchKernelGGL(zero_i32, dim3(nb), dim3(256), 0, stream, cursor, N);
  hipLaunchKernelGGL(count_kernel, dim3(eb), dim3(256), 0, stream, ei, flag, cursor, E);
  hipLaunchKernelGGL(scan1_kernel, dim3(P), dim3(1024), 0, stream, cursor, row_ptr, partials, N);
  hipLaunchKernelGGL(scan2_kernel, dim3(1), dim3(64), 0, stream, partials, P);
  hipLaunchKernelGGL(scan3_kernel, dim3(nb), dim3(256), 0, stream, row_ptr, partials, N, E);
  hipLaunchKernelGGL(copy_i32, dim3(nb), dim3(256), 0, stream, row_ptr, cursor, N);
  hipLaunchKernelGGL(fill_kernel, dim3(eb), dim3(256), 0, stream, ei, flag, cursor, csr, E);

  // weights + x to bf16
  hipLaunchKernelGGL(wtrans_kernel, dim3(256), dim3(256), 0, stream, W1, W1t);
  hipLaunchKernelGGL(wtrans_kernel, dim3(256), dim3(256), 0, stream, W2, W2t);
  hipLaunchKernelGGL(conv_bf16_kernel, dim3((n8 + 255) / 256), dim3(256), 0, stream, x, abf, n8);

  const dim3 gg(2, (N + 127) / 128);  // x = n-tile (L2-friendly: same A rows adjacent), y = m-tile
  hipLaunchKernelGGL(mfma_gemm_kernel, gg, dim3(256), 0, stream, abf, W1t, b1, h, N);
  hipLaunchKernelGGL(gat_fused_kernel, dim3((N + 3) / 4), dim3(256), 0, stream,
                     h, att1, row_ptr, csr, (float*)nullptr, abf, N);  // writes bf16 only
  hipLaunchKernelGGL(mfma_gemm_kernel, gg, dim3(256), 0, stream, abf, W2t, b2, h, N);
  hipLaunchKernelGGL(gat_fused_kernel, dim3((N + 3) / 4), dim3(256), 0, stream,
                     h, att2, row_ptr, csr, g, (unsigned short*)nullptr, N);
  hipLaunchKernelGGL(fuse_w_kernel, dim3(1), dim3(256), 0, stream, Wp1, bp1, Wp2, bp2, Wf, bfv);
  hipLaunchKernelGGL(post_kernel, dim3(1024), dim3(256), 0, stream, g, Wf, bfv, outp, N);
}

// Round 4
// 337.259 us; speedup vs baseline: 2.1052x; 1.1447x over previous
//
#include <hip/hip_runtime.h>
#include <hip/hip_bf16.h>
#include <math.h>

#define HC 256
#define NEG_SLOPE 0.2f

typedef __attribute__((ext_vector_type(8))) short s16x8;
typedef __attribute__((ext_vector_type(4))) float f32x4;

__device__ __forceinline__ unsigned short f2bf(float f) {
  __hip_bfloat16 b = __float2bfloat16(f);
  return *reinterpret_cast<unsigned short*>(&b);
}
__device__ __forceinline__ float bf2f(unsigned short u) {
  unsigned v = ((unsigned)u) << 16;
  return __builtin_bit_cast(float, v);
}

// ---------- edge dtype detection (int32 vs int64) ----------
__global__ void detect_i64_kernel(const int* __restrict__ e, int* __restrict__ flag, int nCheck) {
  if (blockIdx.x == 0 && threadIdx.x == 0) {
    int nz = 0;
    for (int i = 0; i < nCheck; ++i) nz += (e[2 * i + 1] != 0);
    *flag = (nz == 0) ? 1 : 0;  // all-high-words-zero => int64
  }
}

__device__ __forceinline__ int edge_val(const void* p, int is64, long long idx) {
  return is64 ? (int)((const long long*)p)[idx] : ((const int*)p)[idx];
}

__global__ void count_kernel(const void* __restrict__ edges, const int* __restrict__ flag,
                             int* __restrict__ counts, int E) {
  int e = blockIdx.x * blockDim.x + threadIdx.x;
  if (e >= E) return;
  int is64 = *flag;
  int dst = edge_val(edges, is64, (long long)E + e);
  atomicAdd(&counts[dst], 1);
}

__device__ __forceinline__ int wave_incl_scan(int v) {
  int lane = threadIdx.x & 63;
#pragma unroll
  for (int off = 1; off < 64; off <<= 1) {
    int y = __shfl_up(v, off, 64);
    if (lane >= off) v += y;
  }
  return v;
}

__global__ __launch_bounds__(1024) void scan1_kernel(const int* __restrict__ counts,
                                                     int* __restrict__ excl,
                                                     int* __restrict__ partials, int N) {
  __shared__ int wsum[16];
  int i = blockIdx.x * 1024 + threadIdx.x;
  int wid = threadIdx.x >> 6, lane = threadIdx.x & 63;
  int v = (i < N) ? counts[i] : 0;
  int incl = wave_incl_scan(v);
  if (lane == 63) wsum[wid] = incl;
  __syncthreads();
  if (wid == 0) {
    int s = (lane < 16) ? wsum[lane] : 0;
    s = wave_incl_scan(s);
    if (lane < 16) wsum[lane] = s;
  }
  __syncthreads();
  int base = (wid > 0) ? wsum[wid - 1] : 0;
  if (i < N) excl[i] = base + incl - v;
  if (threadIdx.x == 1023) partials[blockIdx.x] = base + incl;
}

__global__ void scan2_kernel(int* __restrict__ partials, int P) {
  int lane = threadIdx.x;
  if (P <= 64) {
    int v = (lane < P) ? partials[lane] : 0;
    int incl = wave_incl_scan(v);
    if (lane < P) partials[lane] = incl - v;
  } else if (lane == 0) {
    int run = 0;
    for (int i = 0; i < P; ++i) { int v = partials[i]; partials[i] = run; run += v; }
  }
}

// add partials, write final row_ptr AND cursor copy in one pass
__global__ void scan3copy_kernel(int* __restrict__ excl, const int* __restrict__ partials,
                                 int* __restrict__ cursor, int N, int E) {
  int i = blockIdx.x * blockDim.x + threadIdx.x;
  if (i < N) {
    int v = excl[i] + partials[i >> 10];
    excl[i] = v;
    cursor[i] = v;
  }
  if (i == 0) excl[N] = E;
}

__global__ void fill_kernel(const void* __restrict__ edges, const int* __restrict__ flag,
                            int* __restrict__ cursor, int* __restrict__ csr_src, int E) {
  int e = blockIdx.x * blockDim.x + threadIdx.x;
  if (e >= E) return;
  int is64 = *flag;
  int src = edge_val(edges, is64, e);
  int dst = edge_val(edges, is64, (long long)E + e);
  int pos = atomicAdd(&cursor[dst], 1);
  csr_src[pos] = src;
}

// ---------- both weight transposes in one launch: Wt[n][k] = bf16(W[k][n]) ----------
__global__ __launch_bounds__(256) void wtrans2_kernel(
    const float* __restrict__ W1, const float* __restrict__ W2,
    unsigned short* __restrict__ W1t, unsigned short* __restrict__ W2t) {
  int n = blockIdx.x & 255, which = blockIdx.x >> 8, t = threadIdx.x;
  const float* W = which ? W2 : W1;
  unsigned short* Wt = which ? W2t : W1t;
  Wt[(size_t)n * 256 + t] = f2bf(W[(size_t)t * 256 + n]);
}

// ---------- bf16 MFMA GEMM: C[M,256] = A[M,256] @ Bt[256,256]^T + bias ----------
// AF32: A is fp32 (converted to bf16 during staging); else A is bf16
template <bool AF32>
__global__ __launch_bounds__(256) void mfma_gemm_kernel(
    const void* __restrict__ Araw, const unsigned short* __restrict__ Bt,
    const float* __restrict__ bias, float* __restrict__ C, int M) {
  __shared__ __align__(16) short As[2][128 * 64];
  __shared__ __align__(16) short Bs[2][128 * 64];
  const int t = threadIdx.x;
  const int l = t & 63, w = t >> 6;
  const int wr = w >> 1, wc = w & 1;
  const int m0 = blockIdx.y * 128, n0 = blockIdx.x * 128;
  const int l15 = l & 15, lg = l >> 4;

  const int ccs = ((t & 7) ^ ((t >> 3) & 7)) * 8;  // swizzled source elem offset
  int rowL[4], ldsI[4];
#pragma unroll
  for (int i = 0; i < 4; ++i) {
    rowL[i] = i * 32 + (t >> 3);
    ldsI[i] = (i * 256 + t) * 8;
  }

  f32x4 acc[4][4];
#pragma unroll
  for (int m = 0; m < 4; ++m)
#pragma unroll
    for (int n = 0; n < 4; ++n) acc[m][n] = (f32x4){0.f, 0.f, 0.f, 0.f};

  uint4 ra[4], rb[4];
  auto LOAD = [&](int ks) {
    int k0 = ks * 64;
#pragma unroll
    for (int i = 0; i < 4; ++i) {
      int ar = m0 + rowL[i];
      ar = (ar < M) ? ar : (M - 1);
      if (AF32) {
        const float* A = (const float*)Araw;
        float4 fa = *(const float4*)(A + (size_t)ar * 256 + k0 + ccs);
        float4 fb = *(const float4*)(A + (size_t)ar * 256 + k0 + ccs + 4);
        ra[i].x = f2bf(fa.x) | ((unsigned)f2bf(fa.y) << 16);
        ra[i].y = f2bf(fa.z) | ((unsigned)f2bf(fa.w) << 16);
        ra[i].z = f2bf(fb.x) | ((unsigned)f2bf(fb.y) << 16);
        ra[i].w = f2bf(fb.z) | ((unsigned)f2bf(fb.w) << 16);
      } else {
        const unsigned short* A = (const unsigned short*)Araw;
        ra[i] = *(const uint4*)(A + (size_t)ar * 256 + k0 + ccs);
      }
      rb[i] = *(const uint4*)(Bt + (size_t)(n0 + rowL[i]) * 256 + k0 + ccs);
    }
  };
  auto WRITE = [&](int buf) {
#pragma unroll
    for (int i = 0; i < 4; ++i) {
      *(uint4*)&As[buf][ldsI[i]] = ra[i];
      *(uint4*)&Bs[buf][ldsI[i]] = rb[i];
    }
  };

  int rA[4], rB[4];
#pragma unroll
  for (int m = 0; m < 4; ++m) rA[m] = (wr * 64 + m * 16 + l15) * 64;
#pragma unroll
  for (int n = 0; n < 4; ++n) rB[n] = (wc * 64 + n * 16 + l15) * 64;
  const int swz0 = ((0 * 4 + lg) ^ (l & 7)) * 8;
  const int swz1 = ((1 * 4 + lg) ^ (l & 7)) * 8;

  LOAD(0);
  WRITE(0);
  __syncthreads();
  for (int ks = 0; ks < 4; ++ks) {
    if (ks < 3) LOAD(ks + 1);
    const int buf = ks & 1;
#pragma unroll
    for (int kk = 0; kk < 2; ++kk) {
      const int swz = kk ? swz1 : swz0;
      s16x8 a[4], b[4];
#pragma unroll
      for (int m = 0; m < 4; ++m) a[m] = *(const s16x8*)&As[buf][rA[m] + swz];
#pragma unroll
      for (int n = 0; n < 4; ++n) b[n] = *(const s16x8*)&Bs[buf][rB[n] + swz];
#pragma unroll
      for (int m = 0; m < 4; ++m)
#pragma unroll
        for (int n = 0; n < 4; ++n)
          acc[m][n] = __builtin_amdgcn_mfma_f32_16x16x32_bf16(a[m], b[n], acc[m][n], 0, 0, 0);
    }
    if (ks < 3) WRITE((ks + 1) & 1);
    __syncthreads();
  }

  float bcol[4];
#pragma unroll
  for (int n = 0; n < 4; ++n) bcol[n] = bias[n0 + wc * 64 + n * 16 + l15];
#pragma unroll
  for (int m = 0; m < 4; ++m) {
    int baseRow = m0 + wr * 64 + m * 16 + lg * 4;
#pragma unroll
    for (int r = 0; r < 4; ++r) {
      int row = baseRow + r;
      if (row < M) {
#pragma unroll
        for (int n = 0; n < 4; ++n)
          C[(size_t)row * 256 + n0 + wc * 64 + n * 16 + l15] = acc[m][n][r] + bcol[n];
      }
    }
  }
}

// ---------- fused GATv2: 1 wave/node, chunk-of-8 batched gathers, deferred max ----------
__global__ __launch_bounds__(256) void gat_fused_kernel(
    const float* __restrict__ h, const float* __restrict__ att,
    const int* __restrict__ row_ptr, const int* __restrict__ csr_src,
    unsigned short* __restrict__ out_bf, int N) {
  int wid = threadIdx.x >> 6, ln = threadIdx.x & 63;
  int node = blockIdx.x * 4 + wid;
  if (node >= N) return;
  const float4 attv = *(const float4*)(att + ln * 4);
  const float4 hi = *(const float4*)(h + (size_t)node * HC + ln * 4);
  int beg = row_ptr[node], end = row_ptr[node + 1];
  float m = -INFINITY, d = 0.f;
  float4 S = make_float4(0.f, 0.f, 0.f, 0.f);

  for (int e0 = beg; e0 < end; e0 += 8) {
    const int cnt = min(8, end - e0);
    // lane-parallel index fetch (lanes 0..7) + broadcast
    int ld = e0 + (ln & 7);
    int myidx = csr_src[(ld < end) ? ld : (end - 1)];
    float4 hj[8];
    float p[8];
#pragma unroll
    for (int c = 0; c < 8; ++c) {
      if (c < cnt) {
        int j = __shfl(myidx, c, 64);
        hj[c] = *(const float4*)(h + (size_t)j * HC + ln * 4);
      }
    }
#pragma unroll
    for (int c = 0; c < 8; ++c) {
      p[c] = -INFINITY;
      if (c < cnt) {
        float4 s4, l4;
        s4.x = hi.x + hj[c].x; s4.y = hi.y + hj[c].y;
        s4.z = hi.z + hj[c].z; s4.w = hi.w + hj[c].w;
        l4.x = fmaxf(s4.x, NEG_SLOPE * s4.x);
        l4.y = fmaxf(s4.y, NEG_SLOPE * s4.y);
        l4.z = fmaxf(s4.z, NEG_SLOPE * s4.z);
        l4.w = fmaxf(s4.w, NEG_SLOPE * s4.w);
        float pp = l4.x * attv.x + l4.y * attv.y + l4.z * attv.z + l4.w * attv.w;
#pragma unroll
        for (int off = 1; off < 16; off <<= 1) pp += __shfl_xor(pp, off, 64);
        p[c] = pp;
      }
    }
    // deferred max: one rescale per chunk
    float mx = m;
#pragma unroll
    for (int c = 0; c < 8; ++c) mx = fmaxf(mx, p[c]);
    float scl = __expf(m - mx);
    d *= scl;
    S.x *= scl; S.y *= scl; S.z *= scl; S.w *= scl;
#pragma unroll
    for (int c = 0; c < 8; ++c) {
      if (c < cnt) {
        float wgt = __expf(p[c] - mx);
        d += wgt;
        S.x += wgt * hj[c].x;
        S.y += wgt * hj[c].y;
        S.z += wgt * hj[c].z;
        S.w += wgt * hj[c].w;
      }
    }
    m = mx;
  }

  float inv = (d > 0.f) ? (1.f / d) : 0.f;
  ushort4 ub;
  ub.x = f2bf(fmaxf(S.x * inv, 0.f));
  ub.y = f2bf(fmaxf(S.y * inv, 0.f));
  ub.z = f2bf(fmaxf(S.z * inv, 0.f));
  ub.w = f2bf(fmaxf(S.w * inv, 0.f));
  *(ushort4*)(out_bf + (size_t)node * HC + ln * 4) = ub;
}

// ---------- fold post_mp: Wf = Wp1@Wp2, bf = bp1@Wp2 + bp2 ----------
__global__ __launch_bounds__(256) void fuse_w_kernel(
    const float* __restrict__ Wp1, const float* __restrict__ bp1,
    const float* __restrict__ Wp2, const float* __restrict__ bp2,
    float* __restrict__ Wf, float* __restrict__ bf) {
  int k = threadIdx.x;
  float acc[32];
#pragma unroll
  for (int o = 0; o < 32; ++o) acc[o] = 0.f;
  for (int ll = 0; ll < 64; ++ll) {
    float w1 = Wp1[k * 64 + ll];
#pragma unroll
    for (int o = 0; o < 32; ++o) acc[o] += w1 * Wp2[ll * 32 + o];
  }
  for (int o = 0; o < 32; ++o) Wf[k * 32 + o] = acc[o];
  if (k < 32) {
    float s = bp2[k];
    for (int ll = 0; ll < 64; ++ll) s += bp1[ll] * Wp2[ll * 32 + k];
    bf[k] = s;
  }
}

// ---------- post: out = sigmoid(g(bf16) @ Wf + bf) ----------
__global__ __launch_bounds__(256) void post_kernel(
    const unsigned short* __restrict__ g, const float* __restrict__ Wf,
    const float* __restrict__ bf, float* __restrict__ out, int Nn) {
  __shared__ float sW[256 * 32];
  __shared__ float sg[8][256];
  for (int i = threadIdx.x; i < 256 * 32; i += 256) sW[i] = Wf[i];
  int o = threadIdx.x & 31, ln = threadIdx.x >> 5;
  float bo = bf[o];
  const int r_st = threadIdx.x >> 5, c_st = (threadIdx.x & 31) * 8;
  for (int base = blockIdx.x * 8; base < Nn; base += gridDim.x * 8) {
    __syncthreads();
    {
      int node = base + r_st;
      uint4 u = make_uint4(0, 0, 0, 0);
      if (node < Nn) u = *(const uint4*)(g + (size_t)node * 256 + c_st);
      sg[r_st][c_st + 0] = bf2f((unsigned short)(u.x & 0xffff));
      sg[r_st][c_st + 1] = bf2f((unsigned short)(u.x >> 16));
      sg[r_st][c_st + 2] = bf2f((unsigned short)(u.y & 0xffff));
      sg[r_st][c_st + 3] = bf2f((unsigned short)(u.y >> 16));
      sg[r_st][c_st + 4] = bf2f((unsigned short)(u.z & 0xffff));
      sg[r_st][c_st + 5] = bf2f((unsigned short)(u.z >> 16));
      sg[r_st][c_st + 6] = bf2f((unsigned short)(u.w & 0xffff));
      sg[r_st][c_st + 7] = bf2f((unsigned short)(u.w >> 16));
    }
    __syncthreads();
    int node = base + ln;
    if (node < Nn) {
      float acc = bo;
#pragma unroll 8
      for (int k = 0; k < 256; ++k) acc += sg[ln][k] * sW[k * 32 + o];
      out[(size_t)node * 32 + o] = 1.f / (1.f + __expf(-acc));
    }
  }
}

extern "C" void kernel_launch(void* const* d_in, const int* in_sizes, int n_in,
                              void* d_out, int out_size, void* d_ws, size_t ws_size,
                              hipStream_t stream) {
  const float* x    = (const float*)d_in[0];
  const void*  ei   = d_in[1];
  const float* W1   = (const float*)d_in[2];
  const float* b1   = (const float*)d_in[3];
  const float* att1 = (const float*)d_in[4];
  const float* W2   = (const float*)d_in[5];
  const float* b2   = (const float*)d_in[6];
  const float* att2 = (const float*)d_in[7];
  const float* Wp1  = (const float*)d_in[8];
  const float* bp1  = (const float*)d_in[9];
  const float* Wp2  = (const float*)d_in[10];
  const float* bp2  = (const float*)d_in[11];
  const int N = in_sizes[0] / 256;
  const int E = in_sizes[1] / 2;
  float* outp = (float*)d_out;

  char* ws = (char*)d_ws;
  size_t off = 0;
  auto alloc = [&](size_t bytes) {
    char* p = ws + off;
    off = (off + bytes + 255) & ~(size_t)255;
    return p;
  };
  float* h        = (float*)alloc((size_t)N * 256 * 4);
  unsigned short* abf  = (unsigned short*)alloc((size_t)N * 256 * 2);  // GAT1 out (bf16)
  unsigned short* g2bf = (unsigned short*)alloc((size_t)N * 256 * 2);  // GAT2 out (bf16)
  int*   row_ptr  = (int*)alloc((size_t)(N + 1) * 4);
  int*   cursor   = (int*)alloc((size_t)N * 4);
  int*   csr      = (int*)alloc((size_t)E * 4);
  int*   partials = (int*)alloc((size_t)((N + 1023) / 1024 + 1) * 4);
  unsigned short* W1t = (unsigned short*)alloc(256 * 256 * 2);
  unsigned short* W2t = (unsigned short*)alloc(256 * 256 * 2);
  float* Wf       = (float*)alloc(256 * 32 * 4);
  float* bfv      = (float*)alloc(32 * 4);
  int*   flag     = (int*)alloc(4);

  const int nb = (N + 255) / 256;
  const int eb = (E + 255) / 256;
  const int P  = (N + 1023) / 1024;

  hipMemsetAsync(cursor, 0, (size_t)N * 4, stream);
  hipLaunchKernelGGL(detect_i64_kernel, dim3(1), dim3(1), 0, stream, (const int*)ei, flag, 64);
  hipLaunchKernelGGL(count_kernel, dim3(eb), dim3(256), 0, stream, ei, flag, cursor, E);
  hipLaunchKernelGGL(scan1_kernel, dim3(P), dim3(1024), 0, stream, cursor, row_ptr, partials, N);
  hipLaunchKernelGGL(scan2_kernel, dim3(1), dim3(64), 0, stream, partials, P);
  hipLaunchKernelGGL(scan3copy_kernel, dim3(nb), dim3(256), 0, stream, row_ptr, partials, cursor, N, E);
  hipLaunchKernelGGL(fill_kernel, dim3(eb), dim3(256), 0, stream, ei, flag, cursor, csr, E);
  hipLaunchKernelGGL(wtrans2_kernel, dim3(512), dim3(256), 0, stream, W1, W2, W1t, W2t);

  const dim3 gg(2, (N + 127) / 128);
  hipLaunchKernelGGL((mfma_gemm_kernel<true>), gg, dim3(256), 0, stream, (const void*)x, W1t, b1, h, N);
  hipLaunchKernelGGL(gat_fused_kernel, dim3((N + 3) / 4), dim3(256), 0, stream,
                     h, att1, row_ptr, csr, abf, N);
  hipLaunchKernelGGL((mfma_gemm_kernel<false>), gg, dim3(256), 0, stream, (const void*)abf, W2t, b2, h, N);
  hipLaunchKernelGGL(gat_fused_kernel, dim3((N + 3) / 4), dim3(256), 0, stream,
                     h, att2, row_ptr, csr, g2bf, N);
  hipLaunchKernelGGL(fuse_w_kernel, dim3(1), dim3(256), 0, stream, Wp1, bp1, Wp2, bp2, Wf, bfv);
  hipLaunchKernelGGL(post_kernel, dim3(1024), dim3(256), 0, stream, g2bf, Wf, bfv, outp, N);
}